// Round 9
// baseline (87.766 us; speedup 1.0000x reference)
//
#include <hip/hip_runtime.h>

// B=16, N=2048, S=SO=12, K=32.
// out[b,i,k,s] = softmax_k( leaky_relu( es[b,i] + ed[b,j] ) ) * x[b,j,s],  j=idx[b,i,k]
//
// Round-9 = round-7/8 theory, compile-fixed: __builtin_nontemporal_store needs
// a NATIVE vector type (clang ext_vector), not HIP's float4 class. Otherwise
// identical to round 4 (best, 85.3):
//  - one 1024-thread block per 128 pairs, full 96 KB batch row table + edt in
//    LDS, ONE barrier, shfl-computed wvec, no-max softmax (guard 80),
//  - dense remapped stores, now non-temporal (50 MB written once, never read:
//    bypass L2 write-allocate churn),
//  - idx loads non-temporal (4 MB single-use stream).

#define GAT_N 2048
#define GAT_ALPHA 0.5f
#define PPBLK 128      // pairs per block
#define THREADS 1024

typedef float nfloat4 __attribute__((ext_vector_type(4)));  // native vec for nt-store

__global__ __launch_bounds__(THREADS, 1) void gat_lds(
    const float* __restrict__ x,    // [B*N, 12]
    const float* __restrict__ W,    // [12,12]
    const float* __restrict__ a,    // [24]
    const int*   __restrict__ idx,  // [B*N, 32]
    float*       __restrict__ out)  // [B*N, 32, 12]
{
    __shared__ float rows[GAT_N * 12];   // 96 KB: full row table of this batch
    __shared__ float edt[GAT_N];         // 8 KB: per-node dst logits
    __shared__ float es_loc[PPBLK];      // per-pair src logits (this block)

    const int tid   = threadIdx.x;
    const int b     = blockIdx.x >> 4;   // batch (16 blocks per batch)
    const int blk16 = blockIdx.x & 15;   // block-in-batch

    const int slot   = tid >> 5;         // pair slot 0..31
    const int k      = tid & 31;         // neighbor slot
    const int pairG0 = (b << 11) + blk16 * PPBLK + slot;

    // ---- prefetch: idx for 4 tasks (non-temporal: single-use stream) ----
    int jv[4];
    #pragma unroll
    for (int t = 0; t < 4; ++t)
        jv[t] = __builtin_nontemporal_load(idx + (size_t)(pairG0 + 32 * t) * 32 + k);

    // ---- prefetch this thread's 2 rows (96 B contiguous) ----
    const float4* gp = (const float4*)(x + (size_t)b * GAT_N * 12 + (size_t)tid * 24);
    const float4 v0 = gp[0], v1 = gp[1], v2 = gp[2];
    const float4 v3 = gp[3], v4 = gp[4], v5 = gp[5];

    // ---- per-wave wvec: lanes 0..23 compute, consumers shfl-broadcast ----
    float acc;
    {
        const int l     = tid & 63;
        const int idx24 = l % 24;
        const int s     = idx24 % 12;
        const float* av = a + (idx24 < 12 ? 0 : 12);
        acc = 0.f;
        #pragma unroll
        for (int t = 0; t < 12; ++t) acc += W[s * 12 + t] * av[t];
    }
    float wvd[12];                        // w_dst
    #pragma unroll
    for (int s = 0; s < 12; ++s) wvd[s] = __shfl(acc, 12 + s, 64);

    // ---- ed for this thread's 2 nodes, from registers ----
    const float ed0 =
        v0.x*wvd[0] + v0.y*wvd[1] + v0.z*wvd[2]  + v0.w*wvd[3] +
        v1.x*wvd[4] + v1.y*wvd[5] + v1.z*wvd[6]  + v1.w*wvd[7] +
        v2.x*wvd[8] + v2.y*wvd[9] + v2.z*wvd[10] + v2.w*wvd[11];
    const float ed1 =
        v3.x*wvd[0] + v3.y*wvd[1] + v3.z*wvd[2]  + v3.w*wvd[3] +
        v4.x*wvd[4] + v4.y*wvd[5] + v4.z*wvd[6]  + v4.w*wvd[7] +
        v5.x*wvd[8] + v5.y*wvd[9] + v5.z*wvd[10] + v5.w*wvd[11];

    // ---- es for the block's 128 pairs (exactly one wave: wave blk16) ----
    if ((tid >> 6) == blk16) {            // wave-uniform branch
        float wvs[12];                    // w_src
        #pragma unroll
        for (int s = 0; s < 12; ++s) wvs[s] = __shfl(acc, s, 64);
        const float es0 =
            v0.x*wvs[0] + v0.y*wvs[1] + v0.z*wvs[2]  + v0.w*wvs[3] +
            v1.x*wvs[4] + v1.y*wvs[5] + v1.z*wvs[6]  + v1.w*wvs[7] +
            v2.x*wvs[8] + v2.y*wvs[9] + v2.z*wvs[10] + v2.w*wvs[11];
        const float es1 =
            v3.x*wvs[0] + v3.y*wvs[1] + v3.z*wvs[2]  + v3.w*wvs[3] +
            v4.x*wvs[4] + v4.y*wvs[5] + v4.z*wvs[6]  + v4.w*wvs[7] +
            v5.x*wvs[8] + v5.y*wvs[9] + v5.z*wvs[10] + v5.w*wvs[11];
        const int local2 = 2 * tid - blk16 * PPBLK;
        es_loc[local2]     = es0;
        es_loc[local2 + 1] = es1;
    }

    // ---- populate LDS: rows (96 B contiguous per thread) + edt ----
    {
        float4* lp = (float4*)(rows + tid * 24);
        lp[0] = v0; lp[1] = v1; lp[2] = v2;
        lp[3] = v3; lp[4] = v4; lp[5] = v5;
        *(float2*)(edt + 2 * tid) = make_float2(ed0, ed1);
    }
    __syncthreads();                      // the ONLY barrier

    // ---- softmax over 32 lanes, 4 tasks/thread ----
    float ex[4], sum[4];
    #pragma unroll
    for (int t = 0; t < 4; ++t) {
        float e = es_loc[slot + 32 * t] + edt[jv[t]];
        e = e > 0.f ? e : GAT_ALPHA * e;
        ex[t]  = __expf(fminf(e, 80.f));
        sum[t] = ex[t];
    }
    #pragma unroll
    for (int off = 16; off; off >>= 1) {
        #pragma unroll
        for (int t = 0; t < 4; ++t) sum[t] += __shfl_xor(sum[t], off, 32);
    }
    float att[4];
    #pragma unroll
    for (int t = 0; t < 4; ++t) att[t] = ex[t] / sum[t];

    // ---- dense NON-TEMPORAL stores via shfl-remap ----
    #pragma unroll
    for (int t = 0; t < 4; ++t) {
        nfloat4* o4 = (nfloat4*)out + (size_t)(pairG0 + 32 * t) * 96;
        #pragma unroll
        for (int r = 0; r < 3; ++r) {
            const int f  = r * 32 + k;
            const int kk = f / 3;
            const int q  = f - 3 * kk;
            const float attk = __shfl(att[t], kk, 32);
            const int   jk   = __shfl(jv[t],  kk, 32);
            const float4 v = *(const float4*)(rows + jk * 12 + 4 * q);
            nfloat4 o;
            o.x = attk * v.x; o.y = attk * v.y; o.z = attk * v.z; o.w = attk * v.w;
            __builtin_nontemporal_store(o, o4 + f);
        }
    }
}

// ---------------- Fallback: verified generic single-kernel path ----------------
__global__ __launch_bounds__(256) void gat_fused(
    const float* __restrict__ x, const float* __restrict__ W,
    const float* __restrict__ a, const int* __restrict__ idx,
    float* __restrict__ out)
{
    __shared__ float wvec[24];
    __shared__ float stage[8 * 384];
    const int tid = threadIdx.x;

    if (tid < 24) {
        const int s = tid % 12;
        const float* av = a + (tid < 12 ? 0 : 12);
        float acc = 0.f;
        #pragma unroll
        for (int t = 0; t < 12; ++t) acc += W[s * 12 + t] * av[t];
        wvec[tid] = acc;
    }
    __syncthreads();

    const int p    = tid >> 5;
    const int pair = blockIdx.x * 8 + p;
    const int k    = tid & 31;

    const float4* rowi = (const float4*)(x + (size_t)pair * 12);
    const float4 i0 = rowi[0], i1 = rowi[1], i2 = rowi[2];
    const float e_src =
        i0.x*wvec[0] + i0.y*wvec[1] + i0.z*wvec[2]  + i0.w*wvec[3] +
        i1.x*wvec[4] + i1.y*wvec[5] + i1.z*wvec[6]  + i1.w*wvec[7] +
        i2.x*wvec[8] + i2.y*wvec[9] + i2.z*wvec[10] + i2.w*wvec[11];

    const int j   = idx[(size_t)pair * 32 + k];
    const int nbr = (pair & ~(GAT_N - 1)) + j;
    const float4* rowj = (const float4*)(x + (size_t)nbr * 12);
    const float4 n0 = rowj[0], n1 = rowj[1], n2 = rowj[2];
    const float e_dst =
        n0.x*wvec[12] + n0.y*wvec[13] + n0.z*wvec[14] + n0.w*wvec[15] +
        n1.x*wvec[16] + n1.y*wvec[17] + n1.z*wvec[18] + n1.w*wvec[19] +
        n2.x*wvec[20] + n2.y*wvec[21] + n2.z*wvec[22] + n2.w*wvec[23];

    float sc = e_src + e_dst;
    sc = sc > 0.f ? sc : GAT_ALPHA * sc;
    float m = sc;
    #pragma unroll
    for (int off = 16; off; off >>= 1) m = fmaxf(m, __shfl_xor(m, off, 32));
    const float ex = __expf(sc - m);
    float sum = ex;
    #pragma unroll
    for (int off = 16; off; off >>= 1) sum += __shfl_xor(sum, off, 32);
    const float att = ex / sum;

    float4* st = (float4*)(stage + p * 384 + k * 12);
    st[0] = make_float4(att * n0.x, att * n0.y, att * n0.z, att * n0.w);
    st[1] = make_float4(att * n1.x, att * n1.y, att * n1.z, att * n1.w);
    st[2] = make_float4(att * n2.x, att * n2.y, att * n2.z, att * n2.w);
    __syncthreads();

    const float4* sm4 = (const float4*)stage;
    float4* o4 = (float4*)(out + (size_t)blockIdx.x * 8 * 384);
    #pragma unroll
    for (int r = 0; r < 3; ++r) o4[tid + 256 * r] = sm4[tid + 256 * r];
}

extern "C" void kernel_launch(void* const* d_in, const int* in_sizes, int n_in,
                              void* d_out, int out_size, void* d_ws, size_t ws_size,
                              hipStream_t stream) {
    // inputs: fushed_features (unused), input_data, W, a, idx
    const float* x   = (const float*)d_in[1];
    const float* W   = (const float*)d_in[2];
    const float* a   = (const float*)d_in[3];
    const int*   idx = (const int*)d_in[4];
    float* out = (float*)d_out;

    const int pairs = in_sizes[1] / 12;    // B*N = 32768 nodes

    if ((pairs & (GAT_N - 1)) == 0) {
        gat_lds<<<pairs / PPBLK, THREADS, 0, stream>>>(x, W, a, idx, out);
    } else {
        gat_fused<<<pairs / 8, 256, 0, stream>>>(x, W, a, idx, out);
    }
}

// Round 10
// 85.831 us; speedup vs baseline: 1.0225x; 1.0225x over previous
//
#include <hip/hip_runtime.h>

// B=16, N=2048, S=SO=12, K=32.
// out[b,i,k,s] = softmax_k( leaky_relu( es[b,i] + ed[b,j] ) ) * x[b,j,s],  j=idx[b,i,k]
//
// FINAL = round-4 exact (best measured: 85.3 µs; round-9's non-temporal
// variant regressed to 87.8). Session findings:
//  - LDS-resident batch row table (96 KB) for the data-dependent gather and
//    fully dense remapped stores are the only load-bearing optimizations
//    (R3: −5.5 µs; removing the table, R5: +10.7 µs),
//  - instruction count, phase structure, barrier count, occupancy, block
//    succession, XCD affinity, non-temporal hints: all individually null or
//    negative (R1/R2/R4-variants/R5/R6/R9),
//  - kernel is at its memory-traffic floor (~13 µs: 50 MB dense store +
//    28 MB reads at the fill-demonstrated 6.1 TB/s); the rest of dur_us is
//    invariant harness overhead (44 µs ws-poison fill + 8.4 µs out poison +
//    dispatch gaps).
//
// Structure: one 1024-thread block per 128 pairs (grid 256 = 1 block/CU),
// full batch row table + per-node ed in LDS, ONE barrier, per-wave shfl
// wvec, no-max softmax (|logit| small, guard 80), dense remapped stores.

#define GAT_N 2048
#define GAT_ALPHA 0.5f
#define PPBLK 128      // pairs per block
#define THREADS 1024

__global__ __launch_bounds__(THREADS, 1) void gat_lds(
    const float* __restrict__ x,    // [B*N, 12]
    const float* __restrict__ W,    // [12,12]
    const float* __restrict__ a,    // [24]
    const int*   __restrict__ idx,  // [B*N, 32]
    float*       __restrict__ out)  // [B*N, 32, 12]
{
    __shared__ float rows[GAT_N * 12];   // 96 KB: full row table of this batch
    __shared__ float edt[GAT_N];         // 8 KB: per-node dst logits
    __shared__ float es_loc[PPBLK];      // per-pair src logits (this block)

    const int tid   = threadIdx.x;
    const int b     = blockIdx.x >> 4;   // batch (16 blocks per batch)
    const int blk16 = blockIdx.x & 15;   // block-in-batch

    const int slot   = tid >> 5;         // pair slot 0..31
    const int k      = tid & 31;         // neighbor slot
    const int pairG0 = (b << 11) + blk16 * PPBLK + slot;

    // ---- prefetch: idx for 4 tasks + this thread's 2 rows (96 B) ----
    int jv[4];
    #pragma unroll
    for (int t = 0; t < 4; ++t)
        jv[t] = idx[(size_t)(pairG0 + 32 * t) * 32 + k];

    const float4* gp = (const float4*)(x + (size_t)b * GAT_N * 12 + (size_t)tid * 24);
    const float4 v0 = gp[0], v1 = gp[1], v2 = gp[2];
    const float4 v3 = gp[3], v4 = gp[4], v5 = gp[5];

    // ---- per-wave wvec: lanes 0..23 compute, consumers shfl-broadcast ----
    float acc;
    {
        const int l     = tid & 63;
        const int idx24 = l % 24;
        const int s     = idx24 % 12;
        const float* av = a + (idx24 < 12 ? 0 : 12);
        acc = 0.f;
        #pragma unroll
        for (int t = 0; t < 12; ++t) acc += W[s * 12 + t] * av[t];
    }
    float wvd[12];                        // w_dst
    #pragma unroll
    for (int s = 0; s < 12; ++s) wvd[s] = __shfl(acc, 12 + s, 64);

    // ---- ed for this thread's 2 nodes, from registers ----
    const float ed0 =
        v0.x*wvd[0] + v0.y*wvd[1] + v0.z*wvd[2]  + v0.w*wvd[3] +
        v1.x*wvd[4] + v1.y*wvd[5] + v1.z*wvd[6]  + v1.w*wvd[7] +
        v2.x*wvd[8] + v2.y*wvd[9] + v2.z*wvd[10] + v2.w*wvd[11];
    const float ed1 =
        v3.x*wvd[0] + v3.y*wvd[1] + v3.z*wvd[2]  + v3.w*wvd[3] +
        v4.x*wvd[4] + v4.y*wvd[5] + v4.z*wvd[6]  + v4.w*wvd[7] +
        v5.x*wvd[8] + v5.y*wvd[9] + v5.z*wvd[10] + v5.w*wvd[11];

    // ---- es for the block's 128 pairs (exactly one wave: wave blk16) ----
    if ((tid >> 6) == blk16) {            // wave-uniform branch
        float wvs[12];                    // w_src
        #pragma unroll
        for (int s = 0; s < 12; ++s) wvs[s] = __shfl(acc, s, 64);
        const float es0 =
            v0.x*wvs[0] + v0.y*wvs[1] + v0.z*wvs[2]  + v0.w*wvs[3] +
            v1.x*wvs[4] + v1.y*wvs[5] + v1.z*wvs[6]  + v1.w*wvs[7] +
            v2.x*wvs[8] + v2.y*wvs[9] + v2.z*wvs[10] + v2.w*wvs[11];
        const float es1 =
            v3.x*wvs[0] + v3.y*wvs[1] + v3.z*wvs[2]  + v3.w*wvs[3] +
            v4.x*wvs[4] + v4.y*wvs[5] + v4.z*wvs[6]  + v4.w*wvs[7] +
            v5.x*wvs[8] + v5.y*wvs[9] + v5.z*wvs[10] + v5.w*wvs[11];
        const int local2 = 2 * tid - blk16 * PPBLK;
        es_loc[local2]     = es0;
        es_loc[local2 + 1] = es1;
    }

    // ---- populate LDS: rows (96 B contiguous per thread) + edt ----
    {
        float4* lp = (float4*)(rows + tid * 24);
        lp[0] = v0; lp[1] = v1; lp[2] = v2;
        lp[3] = v3; lp[4] = v4; lp[5] = v5;
        *(float2*)(edt + 2 * tid) = make_float2(ed0, ed1);
    }
    __syncthreads();                      // the ONLY barrier

    // ---- softmax over 32 lanes, 4 tasks/thread ----
    float ex[4], sum[4];
    #pragma unroll
    for (int t = 0; t < 4; ++t) {
        float e = es_loc[slot + 32 * t] + edt[jv[t]];
        e = e > 0.f ? e : GAT_ALPHA * e;
        ex[t]  = __expf(fminf(e, 80.f));
        sum[t] = ex[t];
    }
    #pragma unroll
    for (int off = 16; off; off >>= 1) {
        #pragma unroll
        for (int t = 0; t < 4; ++t) sum[t] += __shfl_xor(sum[t], off, 32);
    }
    float att[4];
    #pragma unroll
    for (int t = 0; t < 4; ++t) att[t] = ex[t] / sum[t];

    // ---- dense stores via shfl-remap ----
    #pragma unroll
    for (int t = 0; t < 4; ++t) {
        float4* o4 = (float4*)out + (size_t)(pairG0 + 32 * t) * 96;
        #pragma unroll
        for (int r = 0; r < 3; ++r) {
            const int f  = r * 32 + k;
            const int kk = f / 3;
            const int q  = f - 3 * kk;
            const float attk = __shfl(att[t], kk, 32);
            const int   jk   = __shfl(jv[t],  kk, 32);
            const float4 v = *(const float4*)(rows + jk * 12 + 4 * q);
            o4[f] = make_float4(attk * v.x, attk * v.y, attk * v.z, attk * v.w);
        }
    }
}

// ---------------- Fallback: verified generic single-kernel path ----------------
__global__ __launch_bounds__(256) void gat_fused(
    const float* __restrict__ x, const float* __restrict__ W,
    const float* __restrict__ a, const int* __restrict__ idx,
    float* __restrict__ out)
{
    __shared__ float wvec[24];
    __shared__ float stage[8 * 384];
    const int tid = threadIdx.x;

    if (tid < 24) {
        const int s = tid % 12;
        const float* av = a + (tid < 12 ? 0 : 12);
        float acc = 0.f;
        #pragma unroll
        for (int t = 0; t < 12; ++t) acc += W[s * 12 + t] * av[t];
        wvec[tid] = acc;
    }
    __syncthreads();

    const int p    = tid >> 5;
    const int pair = blockIdx.x * 8 + p;
    const int k    = tid & 31;

    const float4* rowi = (const float4*)(x + (size_t)pair * 12);
    const float4 i0 = rowi[0], i1 = rowi[1], i2 = rowi[2];
    const float e_src =
        i0.x*wvec[0] + i0.y*wvec[1] + i0.z*wvec[2]  + i0.w*wvec[3] +
        i1.x*wvec[4] + i1.y*wvec[5] + i1.z*wvec[6]  + i1.w*wvec[7] +
        i2.x*wvec[8] + i2.y*wvec[9] + i2.z*wvec[10] + i2.w*wvec[11];

    const int j   = idx[(size_t)pair * 32 + k];
    const int nbr = (pair & ~(GAT_N - 1)) + j;
    const float4* rowj = (const float4*)(x + (size_t)nbr * 12);
    const float4 n0 = rowj[0], n1 = rowj[1], n2 = rowj[2];
    const float e_dst =
        n0.x*wvec[12] + n0.y*wvec[13] + n0.z*wvec[14] + n0.w*wvec[15] +
        n1.x*wvec[16] + n1.y*wvec[17] + n1.z*wvec[18] + n1.w*wvec[19] +
        n2.x*wvec[20] + n2.y*wvec[21] + n2.z*wvec[22] + n2.w*wvec[23];

    float sc = e_src + e_dst;
    sc = sc > 0.f ? sc : GAT_ALPHA * sc;
    float m = sc;
    #pragma unroll
    for (int off = 16; off; off >>= 1) m = fmaxf(m, __shfl_xor(m, off, 32));
    const float ex = __expf(sc - m);
    float sum = ex;
    #pragma unroll
    for (int off = 16; off; off >>= 1) sum += __shfl_xor(sum, off, 32);
    const float att = ex / sum;

    float4* st = (float4*)(stage + p * 384 + k * 12);
    st[0] = make_float4(att * n0.x, att * n0.y, att * n0.z, att * n0.w);
    st[1] = make_float4(att * n1.x, att * n1.y, att * n1.z, att * n1.w);
    st[2] = make_float4(att * n2.x, att * n2.y, att * n2.z, att * n2.w);
    __syncthreads();

    const float4* sm4 = (const float4*)stage;
    float4* o4 = (float4*)(out + (size_t)blockIdx.x * 8 * 384);
    #pragma unroll
    for (int r = 0; r < 3; ++r) o4[tid + 256 * r] = sm4[tid + 256 * r];
}

extern "C" void kernel_launch(void* const* d_in, const int* in_sizes, int n_in,
                              void* d_out, int out_size, void* d_ws, size_t ws_size,
                              hipStream_t stream) {
    // inputs: fushed_features (unused), input_data, W, a, idx
    const float* x   = (const float*)d_in[1];
    const float* W   = (const float*)d_in[2];
    const float* a   = (const float*)d_in[3];
    const int*   idx = (const int*)d_in[4];
    float* out = (float*)d_out;

    const int pairs = in_sizes[1] / 12;    // B*N = 32768 nodes

    if ((pairs & (GAT_N - 1)) == 0) {
        gat_lds<<<pairs / PPBLK, THREADS, 0, stream>>>(x, W, a, idx, out);
    } else {
        gat_fused<<<pairs / 8, 256, 0, stream>>>(x, W, a, idx, out);
    }
}